// Round 12
// baseline (175.231 us; speedup 1.0000x reference)
//
#include <hip/hip_runtime.h>
#include <stdint.h>

#define NODE_NUM 8192
#define NN 8384        // total nodes per graph (8384 = 131*64)
#define CC 128         // channels
#define BB 2           // batch
#define EE 262144      // edges per graph (2^18)
#define CAP 128        // bucket capacity per (node,kind); max degree ~70 (Poisson)
#define PARTS 8        // XCD-affine partitions (blockIdx & 7)

__device__ __forceinline__ unsigned int f2bf_u(float f) {
  unsigned int u = __float_as_uint(f);
  return (u + 0x7FFFu + ((u >> 16) & 1u)) >> 16;
}
__device__ __forceinline__ float bf2f(unsigned int u) {
  return __uint_as_float(u << 16);
}

// ---- init: 1 wave/node. bf16-pack x AND compute layer-1 projections ----
__global__ void k_init(const float* __restrict__ x, unsigned int* __restrict__ xb,
                       const float* __restrict__ Wi_s, const float* __restrict__ Wj_s,
                       const float* __restrict__ Wi_t, const float* __restrict__ Wj_t,
                       float* __restrict__ pi, float* __restrict__ pj) {
  int wid = (blockIdx.x * blockDim.x + threadIdx.x) >> 6;  // b*NN+n
  int lane = threadIdx.x & 63;
  int n = wid % NN;
  bool is_s = (n < NODE_NUM);
  const float* wi = is_s ? Wi_s : Wi_t;
  const float* wj = is_s ? Wj_s : Wj_t;
  size_t oi = (size_t)wid * (CC / 2) + lane;
  float2 hv = ((const float2*)x)[oi];
  xb[oi] = (f2bf_u(hv.y) << 16) | f2bf_u(hv.x);
  float2 wiv = *(const float2*)(wi + lane * 2);
  float2 wjv = *(const float2*)(wj + lane * 2);
  float a = hv.x * wiv.x + hv.y * wiv.y;
  float c = hv.x * wjv.x + hv.y * wjv.y;
#pragma unroll
  for (int o = 32; o > 0; o >>= 1) {
    a += __shfl_xor(a, o, 64);
    c += __shfl_xor(c, o, 64);
  }
  if (lane == 0) { pi[wid] = a; pj[wid] = c; }
}

// ---- XCD-partitioned single-pass bucketed CSR fill ----
// Partition p = blockIdx&7 (XCD-affine under round-robin dispatch); a block
// only claims edges whose dst&7 == p, so every bucket cache line (node-
// aligned, 512 B) is written by ONE XCD's L2 -> no cross-XCD line ping-pong.
// Each thread scans 8 consecutive edges (all same batch: 2^18 % 8 == 0).
__global__ void k_fill(const int* __restrict__ ei,
                       int* __restrict__ cur_intra, int* __restrict__ cur_inter,
                       int* __restrict__ colS_intra, int* __restrict__ colS_inter) {
  int part = blockIdx.x & (PARTS - 1);
  int group = (blockIdx.x >> 3) * blockDim.x + threadIdx.x;  // 65536 groups
  int eg0 = group * 8;
  int b = eg0 >> 18;
  int e0 = eg0 & (EE - 1);
  const int* eb = ei + b * 2 * EE;
  int4 d0 = *(const int4*)(eb + EE + e0);
  int4 d1 = *(const int4*)(eb + EE + e0 + 4);
  int dsts[8] = {d0.x, d0.y, d0.z, d0.w, d1.x, d1.y, d1.z, d1.w};
#pragma unroll
  for (int k = 0; k < 8; ++k) {
    int dst = dsts[k];
    if ((unsigned)dst >= NN) continue;            // ws-corruption guard
    if ((dst & (PARTS - 1)) != part) continue;    // not ours
    int src = eb[e0 + k];
    if ((unsigned)src >= NN) continue;
    bool ss = (src < NODE_NUM) && (dst < NODE_NUM);
    bool tt = (src >= NODE_NUM) && (dst >= NODE_NUM);
    int node = b * NN + dst;
    if (ss || tt) {
      int pos = atomicAdd(&cur_intra[node], 1);
      if (pos < CAP) colS_intra[(size_t)node * CAP + pos] = src;
    } else {
      int pos = atomicAdd(&cur_inter[node], 1);
      if (pos < CAP) colS_inter[(size_t)node * CAP + pos] = src;
    }
  }
}

// ---- normalization factors from final cursor values (= true degrees) ----
__global__ void k_norms(const int* __restrict__ cur_intra, const int* __restrict__ cur_inter,
                        float* __restrict__ dinv_intra, float* __restrict__ selfnorm,
                        float* __restrict__ dinv_inter) {
  int i = blockIdx.x * blockDim.x + threadIdx.x;
  if (i >= BB * NN) return;
  float df = (float)(cur_intra[i] + 1);   // gcn_norm adds a self loop
  dinv_intra[i] = rsqrtf(df);
  selfnorm[i] = 1.0f / df;
  int di = cur_inter[i];
  dinv_inter[i] = (di > 0) ? (1.0f / (float)di) : 0.0f;
}

// ---- gather: fused edge coefs, bf16 messages, readlane broadcast (no DS ops),
//      bucketed edge lists, fused NEXT-layer projection in the epilogue ----
// 1 wave per dst node; bucket base = wid*CAP (no rowptr). Per 64-edge chunk
// each lane computes one edge's coef; consumption fully unrolled in 8-edge
// sub-chunks with compile-time readlane indices -> SGPR src/coef, 8
// independent message loads in flight, 16 fmas.
template <bool INTRA, bool RELU, bool NEXTPROJ>
__global__ void k_gather(const float* __restrict__ h_in, const unsigned int* __restrict__ hm,
                         float* __restrict__ h_out, unsigned int* __restrict__ hm_out,
                         const int* __restrict__ cnt, const int* __restrict__ colS,
                         const float* __restrict__ pi, const float* __restrict__ pj,
                         const float* __restrict__ normD, const float* __restrict__ normS,
                         const float* __restrict__ selfnorm,
                         const float* __restrict__ nWi_s, const float* __restrict__ nWj_s,
                         const float* __restrict__ nWi_t, const float* __restrict__ nWj_t,
                         float* __restrict__ pi_out, float* __restrict__ pj_out) {
  int wid = (blockIdx.x * blockDim.x + threadIdx.x) >> 6;
  int lane = threadIdx.x & 63;
  int b = wid / NN;
  int n = wid - b * NN;
  int mt = cnt[wid];
  mt = mt < CAP ? mt : CAP;
  const float* hb = h_in + (size_t)b * NN * CC;
  const unsigned int* hmb = hm + (size_t)b * NN * (CC / 2) + lane;
  const float* pjb = pj + b * NN;
  const float* nsb = normS + b * NN;
  float p_i = pi[wid];
  float nd = normD[wid];
  const float2 hv = *(const float2*)(hb + (size_t)n * CC + lane * 2);
  float2 acc;
  if (INTRA) {
    // residual + self-loop message: h * (1 + tanh(pi+pj)/deg)  (fp32 path)
    float fac = 1.0f + tanhf(p_i + pjb[n]) * selfnorm[wid];
    acc.x = hv.x * fac;
    acc.y = hv.y * fac;
  } else {
    acc = hv;  // residual only
  }
  const int* cS = colS + (size_t)wid * CAP;
  for (int off = 0; off < mt; off += 64) {
    int rem = mt - off;
    int m = rem < 64 ? rem : 64;
    int src = 0;
    float c = 0.0f;
    if (lane < m) {
      src = cS[off + lane];
      float a = tanhf(p_i + pjb[src]);
      c = a * nd;
      if (INTRA) c *= nsb[src];
    }
#pragma unroll
    for (int base = 0; base < 64; base += 8) {
      if (base >= m) break;
      unsigned int u[8];
      float cj[8];
#pragma unroll
      for (int k = 0; k < 8; ++k) {
        int sj = __builtin_amdgcn_readlane(src, base + k);          // SGPR
        cj[k] = __int_as_float(
            __builtin_amdgcn_readlane(__float_as_int(c), base + k)); // SGPR
        u[k] = hmb[sj * (CC / 2)];   // saddr-form load, 8 in flight
      }
#pragma unroll
      for (int k = 0; k < 8; ++k) {
        acc.x = fmaf(bf2f(u[k] & 0xFFFFu), cj[k], acc.x);
        acc.y = fmaf(bf2f(u[k] >> 16), cj[k], acc.y);
      }
    }
  }
  if (RELU) { acc.x = fmaxf(acc.x, 0.0f); acc.y = fmaxf(acc.y, 0.0f); }
  size_t oi = (size_t)wid * (CC / 2) + lane;
  *(float2*)(h_out + 2 * oi) = acc;
  if (NEXTPROJ) {
    hm_out[oi] = (f2bf_u(acc.y) << 16) | f2bf_u(acc.x);
    // fused projection for the NEXT layer on the post-activation state
    bool is_s = (n < NODE_NUM);
    const float* wi = is_s ? nWi_s : nWi_t;
    const float* wj = is_s ? nWj_s : nWj_t;
    float2 wiv = *(const float2*)(wi + lane * 2);
    float2 wjv = *(const float2*)(wj + lane * 2);
    float a = acc.x * wiv.x + acc.y * wiv.y;
    float c2 = acc.x * wjv.x + acc.y * wjv.y;
#pragma unroll
    for (int o = 32; o > 0; o >>= 1) {
      a += __shfl_xor(a, o, 64);
      c2 += __shfl_xor(c2, o, 64);
    }
    if (lane == 0) { pi_out[wid] = a; pj_out[wid] = c2; }
  }
}

extern "C" void kernel_launch(void* const* d_in, const int* in_sizes, int n_in,
                              void* d_out, int out_size, void* d_ws, size_t ws_size,
                              hipStream_t stream) {
  const float* x = (const float*)d_in[0];      // fp32 features [B,N,C]
  const int* ei = (const int*)d_in[1];         // int32 [B,2,E]
  const float* Wss = (const float*)d_in[2];    // fp32 [2, 2C]
  const float* Wtt = (const float*)d_in[3];
  const float* Wst = (const float*)d_in[4];
  const float* Wts = (const float*)d_in[5];
  float* out = (float*)d_out;                  // fp32 output [B,N,C]

  char* p = (char*)d_ws;
  auto alloc = [&](size_t bytes) {
    void* r = (void*)p;
    p += ((bytes + 255) & ~(size_t)255);
    return r;
  };
  float* h0 = (float*)alloc((size_t)BB * NN * CC * 4);
  float* h1 = (float*)alloc((size_t)BB * NN * CC * 4);
  unsigned int* xb = (unsigned int*)alloc((size_t)BB * NN * CC * 2);  // bf16 mirrors
  unsigned int* mb0 = (unsigned int*)alloc((size_t)BB * NN * CC * 2);
  unsigned int* mb1 = (unsigned int*)alloc((size_t)BB * NN * CC * 2);
  float* pi0 = (float*)alloc(BB * NN * 4);
  float* pj0 = (float*)alloc(BB * NN * 4);
  float* pi1 = (float*)alloc(BB * NN * 4);
  float* pj1 = (float*)alloc(BB * NN * 4);
  float* dinv_intra = (float*)alloc(BB * NN * 4);
  float* selfnorm = (float*)alloc(BB * NN * 4);
  float* dinv_inter = (float*)alloc(BB * NN * 4);
  int* cur_intra = (int*)alloc(BB * NN * 4);   // cur_intra/cur_inter contiguous
  int* cur_inter = (int*)alloc(BB * NN * 4);   // (67072 % 256 == 0) -> one memset
  int* colS_intra = (int*)alloc((size_t)BB * NN * CAP * 4);  // 8.6 MB buckets
  int* colS_inter = (int*)alloc((size_t)BB * NN * CAP * 4);
  // total ws use: ~46 MB

  hipMemsetAsync(cur_intra, 0, (size_t)2 * BB * NN * 4, stream);

  const int NODE_BLOCKS = (BB * NN * 64) / 256;  // 1 wave per node, 4 waves/block
  const float* wss0 = Wss, *wtt0 = Wtt, *wst0 = Wst, *wts0 = Wts;
  const float* wss1 = Wss + 256, *wtt1 = Wtt + 256, *wst1 = Wst + 256, *wts1 = Wts + 256;

  // pack x -> bf16 mirror + layer-1 (intra) projections
  k_init<<<NODE_BLOCKS, 256, 0, stream>>>(x, xb, wss0, wss0 + 128, wtt0, wtt0 + 128,
                                          pi0, pj0);
  k_fill<<<(BB * EE) / 256, 256, 0, stream>>>(ei, cur_intra, cur_inter,
                                              colS_intra, colS_inter);
  k_norms<<<(BB * NN + 255) / 256, 256, 0, stream>>>(cur_intra, cur_inter,
                                                     dinv_intra, selfnorm, dinv_inter);

  // layer 1 (intra, relu): (x,xb) -> (h0,mb0); fused proj for layer 2 (inter)
  // inter proj: s-node pi=W_ts[:C], pj=W_st[C:]; t-node pi=W_st[:C], pj=W_ts[C:]
  k_gather<true, true, true><<<NODE_BLOCKS, 256, 0, stream>>>(
      x, xb, h0, mb0, cur_intra, colS_intra, pi0, pj0, dinv_intra, dinv_intra, selfnorm,
      wts0, wst0 + 128, wst0, wts0 + 128, pi1, pj1);

  // layer 2 (inter, relu): (h0,mb0) -> (h1,mb1); fused proj for layer 3 (intra)
  k_gather<false, true, true><<<NODE_BLOCKS, 256, 0, stream>>>(
      h0, mb0, h1, mb1, cur_inter, colS_inter, pi1, pj1, dinv_inter, dinv_inter, selfnorm,
      wss1, wss1 + 128, wtt1, wtt1 + 128, pi0, pj0);

  // layer 3 (intra, relu): (h1,mb1) -> (h0,mb0); fused proj for layer 4 (inter)
  k_gather<true, true, true><<<NODE_BLOCKS, 256, 0, stream>>>(
      h1, mb1, h0, mb0, cur_intra, colS_intra, pi0, pj0, dinv_intra, dinv_intra, selfnorm,
      wts1, wst1 + 128, wst1, wts1 + 128, pi1, pj1);

  // layer 4 (inter, no relu): (h0,mb0) -> d_out; no next proj
  k_gather<false, false, false><<<NODE_BLOCKS, 256, 0, stream>>>(
      h0, mb0, out, nullptr, cur_inter, colS_inter, pi1, pj1, dinv_inter, dinv_inter,
      selfnorm, nullptr, nullptr, nullptr, nullptr, nullptr, nullptr);
}